// Round 1
// baseline (142.329 us; speedup 1.0000x reference)
//
#include <hip/hip_runtime.h>
#include <math.h>

// Problem constants: B=2, C=256, H=W=64 -> HW=4096
#define BB 2
#define CC 256
#define CCP (CC + 2)       // LDS pad for prep transpose stores
#define HWN 4096
#define PT 32              // pixels per prep block
#define TM 128             // GEMM block tile (M and N)
#define GEMM_BLOCKS ((HWN / TM) * (HWN / TM) * BB)   // 2048

typedef __attribute__((ext_vector_type(4))) int   intx4;
typedef __attribute__((ext_vector_type(8))) int   intx8;
typedef __attribute__((ext_vector_type(4))) float floatx4;

__device__ __forceinline__ unsigned short f2bf(float f) {
    union { float f; unsigned u; } v; v.f = f;
    unsigned r = v.u + 0x7FFF + ((v.u >> 16) & 1);   // round-to-nearest-even
    return (unsigned short)(r >> 16);
}

__device__ __forceinline__ float bf2f(unsigned short h) {
    union { unsigned u; float f; } v; v.u = ((unsigned)h) << 16;
    return v.f;
}

// async global->LDS, 16B per lane. LDS dest is wave-uniform base + lane*16.
__device__ __forceinline__ void load_lds16(const void* g, void* l) {
    __builtin_amdgcn_global_load_lds(
        (const __attribute__((address_space(1))) unsigned int*)g,
        (__attribute__((address_space(3))) unsigned int*)l, 16, 0, 0);
}

// One block per (batch, 32-pixel chunk), 1024 threads. Computes per-pixel
// channel norms, writes A=norm(dv), D=norm(df)-norm(di) transposed to
// [b][pixel][channel] fp8-e4m3 (K-contiguous for MFMA).
// Round-4 change: float4 loads (4 pixels x 1 channel per thread per pass,
// 2 passes over channels) — 24 scalar global loads -> 6 dwordx4 per thread.
// Per-pixel square-sums folded via stride-8 shfl_xor butterfly (lanes with
// equal p4 share pixels) so LDS atomic count stays at 12 per 8 lanes.
__global__ __launch_bounds__(1024) void prep_kernel(
    const float* __restrict__ sv, const float* __restrict__ si,
    const float* __restrict__ sf, const float* __restrict__ dv,
    const float* __restrict__ di, const float* __restrict__ df,
    unsigned char* __restrict__ Af8, unsigned char* __restrict__ Df8,
    float* __restrict__ pk, float* __restrict__ pd,
    unsigned int* __restrict__ cnt)
{
    __shared__ unsigned short lv[PT][CCP];
    __shared__ unsigned short li[PT][CCP];
    __shared__ unsigned short lf[PT][CCP];
    __shared__ float ssq[3][PT];
    __shared__ float inv[3][PT];
    __shared__ float sdesc;

    const int b   = blockIdx.x / (HWN / PT);
    const int p0  = (blockIdx.x % (HWN / PT)) * PT;
    const int tid = threadIdx.x;
    const int p4  = tid & 7;          // pixel quad: pixels 4*p4 .. 4*p4+3
    const int cg  = tid >> 3;         // channel 0..127 (+128 on pass 1)

    if (blockIdx.x == 0 && tid == 0) cnt[0] = 0u;   // gemm's done-counter
    if (tid < 3 * PT) ((float*)ssq)[tid] = 0.0f;
    if (tid == 0) sdesc = 0.0f;
    __syncthreads();

    float sq[3][4];
    #pragma unroll
    for (int j = 0; j < 3; ++j)
        #pragma unroll
        for (int k = 0; k < 4; ++k) sq[j][k] = 0.0f;
    float descp = 0.f;

    #pragma unroll
    for (int pass = 0; pass < 2; ++pass) {
        const int c = cg + pass * 128;
        const size_t idx = (size_t)b * CC * HWN + (size_t)c * HWN + p0 + p4 * 4;
        const floatx4 v = *(const floatx4*)(dv + idx);   // coalesced dwordx4
        const floatx4 w = *(const floatx4*)(di + idx);
        const floatx4 f = *(const floatx4*)(df + idx);
        #pragma unroll
        for (int k = 0; k < 4; ++k) {
            sq[0][k] += v[k] * v[k];
            sq[1][k] += w[k] * w[k];
            sq[2][k] += f[k] * f[k];
            descp += fabsf(f[k] - 0.5f * (v[k] + w[k]));
            // transpose store: row = pixel, col = channel (2-way bank = free)
            lv[p4 * 4 + k][c] = f2bf(v[k]);
            li[p4 * 4 + k][c] = f2bf(w[k]);
            lf[p4 * 4 + k][c] = f2bf(f[k]);
        }
    }

    // butterfly over the 8 channel-lanes sharing this pixel quad
    #pragma unroll
    for (int m = 8; m < 64; m <<= 1) {
        #pragma unroll
        for (int j = 0; j < 3; ++j)
            #pragma unroll
            for (int k = 0; k < 4; ++k)
                sq[j][k] += __shfl_xor(sq[j][k], m);
    }
    if ((tid & 63) < 8) {       // one lane per pixel quad per wave
        #pragma unroll
        for (int j = 0; j < 3; ++j)
            #pragma unroll
            for (int k = 0; k < 4; ++k)
                atomicAdd(&ssq[j][p4 * 4 + k], sq[j][k]);
    }

    // desc partial: wave reduce, one LDS atomic per wave
    #pragma unroll
    for (int off = 32; off > 0; off >>= 1) descp += __shfl_down(descp, off);
    if ((tid & 63) == 0) atomicAdd(&sdesc, descp);

    // kp term: this block's 32 pixels, float4 loads by lanes 0..7
    if (tid < 64) {
        float kpv = 0.f;
        if (tid < 8) {
            const size_t sidx = (size_t)b * HWN + p0 + tid * 4;
            const floatx4 a  = *(const floatx4*)(sv + sidx);
            const floatx4 bq = *(const floatx4*)(si + sidx);
            const floatx4 cq = *(const floatx4*)(sf + sidx);
            #pragma unroll
            for (int k = 0; k < 4; ++k)
                kpv += fabsf(cq[k] - fmaxf(a[k], bq[k]));
        }
        #pragma unroll
        for (int off = 4; off > 0; off >>= 1) kpv += __shfl_down(kpv, off);
        if (tid == 0) pk[blockIdx.x] = kpv;
    }
    __syncthreads();

    if (tid < 3 * PT) {
        const float s = ((float*)ssq)[tid];
        ((float*)inv)[tid] = 1.0f / fmaxf(sqrtf(s), 1e-12f);
    }
    __syncthreads();

    if (tid == 0) pd[blockIdx.x] = sdesc;

    // Write phase: pack 4 channels per int via v_cvt_pk_fp8_f32 (RNE),
    // coalesced dword stores. 2048 ints / 1024 threads = 2 each.
    int* Ao = (int*)(Af8 + ((size_t)b * HWN + p0) * CC);
    int* Do = (int*)(Df8 + ((size_t)b * HWN + p0) * CC);
    #pragma unroll
    for (int i = tid; i < PT * CC / 4; i += 1024) {
        const int p = i >> 6, c0 = (i & 63) * 4;
        const float ia = inv[0][p], ib = inv[1][p], ic = inv[2][p];
        float a0 = bf2f(lv[p][c0 + 0]) * ia, a1 = bf2f(lv[p][c0 + 1]) * ia;
        float a2 = bf2f(lv[p][c0 + 2]) * ia, a3 = bf2f(lv[p][c0 + 3]) * ia;
        float d0 = bf2f(lf[p][c0 + 0]) * ic - bf2f(li[p][c0 + 0]) * ib;
        float d1 = bf2f(lf[p][c0 + 1]) * ic - bf2f(li[p][c0 + 1]) * ib;
        float d2 = bf2f(lf[p][c0 + 2]) * ic - bf2f(li[p][c0 + 2]) * ib;
        float d3 = bf2f(lf[p][c0 + 3]) * ic - bf2f(li[p][c0 + 3]) * ib;
        int wa = __builtin_amdgcn_cvt_pk_fp8_f32(a0, a1, 0, false);
        wa     = __builtin_amdgcn_cvt_pk_fp8_f32(a2, a3, wa, true);
        int wd = __builtin_amdgcn_cvt_pk_fp8_f32(d0, d1, 0, false);
        wd     = __builtin_amdgcn_cvt_pk_fp8_f32(d2, d3, wd, true);
        Ao[i] = wa;
        Do[i] = wd;
    }
}

// Per batch: S = A_rows · D_rows^T, K=256, fp8-e4m3, MX-scaled MFMA
// (16x16x128, unit scales) -> 2x MFMA rate vs bf16 and only TWO k-steps.
// Whole K staged once into LDS (32KB+32KB), single barrier, no K-loop.
// 4-bit XOR swizzle (16 chunks of 16B per 256B row): staging stays
// lane-contiguous (global_load_lds HW requirement) while ds_read_b128 of
// 16 same-chunk rows spreads across banks (2-way = free).
// Epilogue: |.|-sum (invariant to any output permutation; A/B share the
// lane->k mapping so k-permutations cancel too) -> per-wave partial store.
// Round-4 change: final reduction fused via last-block-done (device-scope
// counter + __threadfence release/acquire; counter zeroed by prep, which
// is stream-ordered before us). Saves the 3rd kernel launch.
__global__ __launch_bounds__(256) void gemm_abs_kernel(
    const unsigned char* __restrict__ Af8,
    const unsigned char* __restrict__ Df8,
    float* __restrict__ pg, const float* __restrict__ pk,
    const float* __restrict__ pd, unsigned int* __restrict__ cnt,
    float* __restrict__ out)
{
    __shared__ unsigned char lA[TM * CC];  // 32 KB
    __shared__ unsigned char lB[TM * CC];  // 32 KB
    __shared__ float ws4[4];
    __shared__ unsigned lastf;

    const int b    = blockIdx.z;
    const int bm   = blockIdx.x * TM;
    const int bn   = blockIdx.y * TM;
    const int tid  = threadIdx.x;
    const int wave = tid >> 6;
    const int lane = tid & 63;
    const int wr   = wave >> 1, wc = wave & 1;

    const unsigned char* Agb = Af8 + (size_t)b * HWN * CC + (size_t)bm * CC;
    const unsigned char* Dgb = Df8 + (size_t)b * HWN * CC + (size_t)bn * CC;

    // Stage all of K: each wave covers rows [wave*32, wave*32+32) of both
    // tiles; one wave-op = 4 rows (64 lanes x 16B). Lane fetches the global
    // chunk that lands swizzled: store-chunk s=lane&15 holds logical chunk
    // s^(r&15).
    #pragma unroll
    for (int i = 0; i < 8; ++i) {
        const int r0 = wave * 32 + i * 4;
        const int r  = r0 + (lane >> 4);
        const int cs = (lane & 15) ^ (r & 15);
        const size_t gof = (size_t)r * CC + cs * 16;
        load_lds16(Agb + gof, (char*)lA + r0 * CC);
        load_lds16(Dgb + gof, (char*)lB + r0 * CC);
    }
    __syncthreads();   // vmcnt(0) drain: all staging visible

    floatx4 accf[4][4];
    #pragma unroll
    for (int mi = 0; mi < 4; ++mi)
        #pragma unroll
        for (int ni = 0; ni < 4; ++ni)
            accf[mi][ni] = (floatx4){0.f, 0.f, 0.f, 0.f};

    #pragma unroll
    for (int ks = 0; ks < 2; ++ks) {
        const int cb = ks * 8 + (lane >> 4) * 2;   // logical 16B chunk pair
        intx8 a8[4], b8[4];
        #pragma unroll
        for (int mi = 0; mi < 4; ++mi) {
            const int m = wr * 64 + mi * 16 + (lane & 15);
            const char* pa = (const char*)lA + m * CC;
            intx4 lo = *(const intx4*)(pa + ((cb    ) ^ (m & 15)) * 16);
            intx4 hi = *(const intx4*)(pa + ((cb + 1) ^ (m & 15)) * 16);
            a8[mi] = __builtin_shufflevector(lo, hi, 0, 1, 2, 3, 4, 5, 6, 7);
        }
        #pragma unroll
        for (int ni = 0; ni < 4; ++ni) {
            const int n = wc * 64 + ni * 16 + (lane & 15);
            const char* pb = (const char*)lB + n * CC;
            intx4 lo = *(const intx4*)(pb + ((cb    ) ^ (n & 15)) * 16);
            intx4 hi = *(const intx4*)(pb + ((cb + 1) ^ (n & 15)) * 16);
            b8[ni] = __builtin_shufflevector(lo, hi, 0, 1, 2, 3, 4, 5, 6, 7);
        }
        #pragma unroll
        for (int mi = 0; mi < 4; ++mi)
            #pragma unroll
            for (int ni = 0; ni < 4; ++ni)
                accf[mi][ni] = __builtin_amdgcn_mfma_scale_f32_16x16x128_f8f6f4(
                    a8[mi], b8[ni], accf[mi][ni],
                    0, 0,                      // cbsz=fp8, blgp=fp8
                    0, 0x7F7F7F7F,             // A scales: E8M0 1.0
                    0, 0x7F7F7F7F);            // B scales: E8M0 1.0
    }

    float s = 0.f;
    #pragma unroll
    for (int mi = 0; mi < 4; ++mi)
        #pragma unroll
        for (int ni = 0; ni < 4; ++ni)
            #pragma unroll
            for (int r = 0; r < 4; ++r)
                s += fabsf(accf[mi][ni][r]);
    #pragma unroll
    for (int off = 32; off > 0; off >>= 1) s += __shfl_down(s, off);
    const int flat = blockIdx.x + 32 * (blockIdx.y + 32 * blockIdx.z);
    if (lane == 0) pg[flat * 4 + wave] = s;   // per-wave partial

    // ---- last-block-done final reduction (replaces final_kernel) ----
    __syncthreads();                       // drains vmcnt: partials in L2
    if (tid == 0) {
        __threadfence();                   // release: writeback for other XCDs
        lastf = (atomicAdd(cnt, 1u) == (unsigned)(GEMM_BLOCKS - 1)) ? 1u : 0u;
    }
    __syncthreads();
    if (lastf) {
        __threadfence();                   // acquire: invalidate stale L2 lines
        float s2 = 0.f;
        #pragma unroll
        for (int i = 0; i < 32; ++i)
            s2 += pg[tid + i * 256];
        s2 *= (1.0f / 33554432.0f);                // match / (B*HW*HW)
        s2 += pk[tid] * (1.0f / 8192.0f)           // kp / (B*HW)
            + pd[tid] * (1.0f / 2097152.0f);       // desc / (B*C*HW)
        #pragma unroll
        for (int off = 32; off > 0; off >>= 1) s2 += __shfl_down(s2, off);
        if ((tid & 63) == 0) ws4[tid >> 6] = s2;
        __syncthreads();
        if (tid == 0) out[0] = ws4[0] + ws4[1] + ws4[2] + ws4[3];
    }
}

extern "C" void kernel_launch(void* const* d_in, const int* in_sizes, int n_in,
                              void* d_out, int out_size, void* d_ws, size_t ws_size,
                              hipStream_t stream) {
    const float* sv = (const float*)d_in[0];
    const float* si = (const float*)d_in[1];
    const float* sf = (const float*)d_in[2];
    const float* dv = (const float*)d_in[3];
    const float* di = (const float*)d_in[4];
    const float* df = (const float*)d_in[5];

    unsigned char* Af8 = (unsigned char*)d_ws;                 // 2 MB
    unsigned char* Df8 = Af8 + (size_t)BB * HWN * CC;          // 2 MB
    float* pg = (float*)(Df8 + (size_t)BB * HWN * CC);         // 32 KB (8192)
    float* pk = pg + 8192;                                     // 1 KB (256)
    float* pd = pk + 256;                                      // 1 KB (256)
    unsigned int* cnt = (unsigned int*)(pd + 256);             // 4 B

    prep_kernel<<<dim3(BB * (HWN / PT)), 1024, 0, stream>>>(
        sv, si, sf, dv, di, df, Af8, Df8, pk, pd, cnt);
    gemm_abs_kernel<<<dim3(HWN / TM, HWN / TM, BB), 256, 0, stream>>>(
        Af8, Df8, pg, pk, pd, cnt, (float*)d_out);
}

// Round 2
// 96.857 us; speedup vs baseline: 1.4695x; 1.4695x over previous
//
#include <hip/hip_runtime.h>
#include <math.h>

// Problem constants: B=2, C=256, H=W=64 -> HW=4096
#define BB 2
#define CC 256
#define CCP (CC + 2)       // LDS pad for prep transpose stores
#define HWN 4096
#define PT 32              // pixels per prep block
#define TM 128             // GEMM block tile (M and N)

typedef __attribute__((ext_vector_type(4))) int   intx4;
typedef __attribute__((ext_vector_type(8))) int   intx8;
typedef __attribute__((ext_vector_type(4))) float floatx4;

__device__ __forceinline__ unsigned short f2bf(float f) {
    union { float f; unsigned u; } v; v.f = f;
    unsigned r = v.u + 0x7FFF + ((v.u >> 16) & 1);   // round-to-nearest-even
    return (unsigned short)(r >> 16);
}

__device__ __forceinline__ float bf2f(unsigned short h) {
    union { unsigned u; float f; } v; v.u = ((unsigned)h) << 16;
    return v.f;
}

// async global->LDS, 16B per lane. LDS dest is wave-uniform base + lane*16.
__device__ __forceinline__ void load_lds16(const void* g, void* l) {
    __builtin_amdgcn_global_load_lds(
        (const __attribute__((address_space(1))) unsigned int*)g,
        (__attribute__((address_space(3))) unsigned int*)l, 16, 0, 0);
}

// One block per (batch, 32-pixel chunk), 1024 threads. Computes per-pixel
// channel norms, writes A=norm(dv), D=norm(df)-norm(di) transposed to
// [b][pixel][channel] fp8-e4m3 (K-contiguous for MFMA).
// float4 loads: 4 pixels x 1 channel per thread per pass, 2 channel passes
// -> 6 dwordx4 global loads per thread (was 24 scalar). Per-pixel square
// sums folded via stride-8 shfl_xor butterfly before LDS atomics.
// NOTE (round-1 post-mortem): do NOT fuse the final reduction into the
// GEMM via last-block-done — the per-block device-scope __threadfence
// (L2 writeback) + same-address atomic round-trip cost +46 us wall.
__global__ __launch_bounds__(1024) void prep_kernel(
    const float* __restrict__ sv, const float* __restrict__ si,
    const float* __restrict__ sf, const float* __restrict__ dv,
    const float* __restrict__ di, const float* __restrict__ df,
    unsigned char* __restrict__ Af8, unsigned char* __restrict__ Df8,
    float* __restrict__ pk, float* __restrict__ pd)
{
    __shared__ unsigned short lv[PT][CCP];
    __shared__ unsigned short li[PT][CCP];
    __shared__ unsigned short lf[PT][CCP];
    __shared__ float ssq[3][PT];
    __shared__ float inv[3][PT];
    __shared__ float sdesc;

    const int b   = blockIdx.x / (HWN / PT);
    const int p0  = (blockIdx.x % (HWN / PT)) * PT;
    const int tid = threadIdx.x;
    const int p4  = tid & 7;          // pixel quad: pixels 4*p4 .. 4*p4+3
    const int cg  = tid >> 3;         // channel 0..127 (+128 on pass 1)

    if (tid < 3 * PT) ((float*)ssq)[tid] = 0.0f;
    if (tid == 0) sdesc = 0.0f;
    __syncthreads();

    float sq[3][4];
    #pragma unroll
    for (int j = 0; j < 3; ++j)
        #pragma unroll
        for (int k = 0; k < 4; ++k) sq[j][k] = 0.0f;
    float descp = 0.f;

    #pragma unroll
    for (int pass = 0; pass < 2; ++pass) {
        const int c = cg + pass * 128;
        const size_t idx = (size_t)b * CC * HWN + (size_t)c * HWN + p0 + p4 * 4;
        const floatx4 v = *(const floatx4*)(dv + idx);   // coalesced dwordx4
        const floatx4 w = *(const floatx4*)(di + idx);
        const floatx4 f = *(const floatx4*)(df + idx);
        #pragma unroll
        for (int k = 0; k < 4; ++k) {
            sq[0][k] += v[k] * v[k];
            sq[1][k] += w[k] * w[k];
            sq[2][k] += f[k] * f[k];
            descp += fabsf(f[k] - 0.5f * (v[k] + w[k]));
            // transpose store: row = pixel, col = channel (2-way bank = free)
            lv[p4 * 4 + k][c] = f2bf(v[k]);
            li[p4 * 4 + k][c] = f2bf(w[k]);
            lf[p4 * 4 + k][c] = f2bf(f[k]);
        }
    }

    // butterfly over the 8 channel-lanes sharing this pixel quad
    #pragma unroll
    for (int m = 8; m < 64; m <<= 1) {
        #pragma unroll
        for (int j = 0; j < 3; ++j)
            #pragma unroll
            for (int k = 0; k < 4; ++k)
                sq[j][k] += __shfl_xor(sq[j][k], m);
    }
    if ((tid & 63) < 8) {       // one lane per pixel quad per wave
        #pragma unroll
        for (int j = 0; j < 3; ++j)
            #pragma unroll
            for (int k = 0; k < 4; ++k)
                atomicAdd(&ssq[j][p4 * 4 + k], sq[j][k]);
    }

    // desc partial: wave reduce, one LDS atomic per wave
    #pragma unroll
    for (int off = 32; off > 0; off >>= 1) descp += __shfl_down(descp, off);
    if ((tid & 63) == 0) atomicAdd(&sdesc, descp);

    // kp term: this block's 32 pixels, float4 loads by lanes 0..7
    if (tid < 64) {
        float kpv = 0.f;
        if (tid < 8) {
            const size_t sidx = (size_t)b * HWN + p0 + tid * 4;
            const floatx4 a  = *(const floatx4*)(sv + sidx);
            const floatx4 bq = *(const floatx4*)(si + sidx);
            const floatx4 cq = *(const floatx4*)(sf + sidx);
            #pragma unroll
            for (int k = 0; k < 4; ++k)
                kpv += fabsf(cq[k] - fmaxf(a[k], bq[k]));
        }
        #pragma unroll
        for (int off = 4; off > 0; off >>= 1) kpv += __shfl_down(kpv, off);
        if (tid == 0) pk[blockIdx.x] = kpv;
    }
    __syncthreads();

    if (tid < 3 * PT) {
        const float s = ((float*)ssq)[tid];
        ((float*)inv)[tid] = 1.0f / fmaxf(sqrtf(s), 1e-12f);
    }
    __syncthreads();

    if (tid == 0) pd[blockIdx.x] = sdesc;

    // Write phase: pack 4 channels per int via v_cvt_pk_fp8_f32 (RNE),
    // coalesced dword stores. 2048 ints / 1024 threads = 2 each.
    int* Ao = (int*)(Af8 + ((size_t)b * HWN + p0) * CC);
    int* Do = (int*)(Df8 + ((size_t)b * HWN + p0) * CC);
    #pragma unroll
    for (int i = tid; i < PT * CC / 4; i += 1024) {
        const int p = i >> 6, c0 = (i & 63) * 4;
        const float ia = inv[0][p], ib = inv[1][p], ic = inv[2][p];
        float a0 = bf2f(lv[p][c0 + 0]) * ia, a1 = bf2f(lv[p][c0 + 1]) * ia;
        float a2 = bf2f(lv[p][c0 + 2]) * ia, a3 = bf2f(lv[p][c0 + 3]) * ia;
        float d0 = bf2f(lf[p][c0 + 0]) * ic - bf2f(li[p][c0 + 0]) * ib;
        float d1 = bf2f(lf[p][c0 + 1]) * ic - bf2f(li[p][c0 + 1]) * ib;
        float d2 = bf2f(lf[p][c0 + 2]) * ic - bf2f(li[p][c0 + 2]) * ib;
        float d3 = bf2f(lf[p][c0 + 3]) * ic - bf2f(li[p][c0 + 3]) * ib;
        int wa = __builtin_amdgcn_cvt_pk_fp8_f32(a0, a1, 0, false);
        wa     = __builtin_amdgcn_cvt_pk_fp8_f32(a2, a3, wa, true);
        int wd = __builtin_amdgcn_cvt_pk_fp8_f32(d0, d1, 0, false);
        wd     = __builtin_amdgcn_cvt_pk_fp8_f32(d2, d3, wd, true);
        Ao[i] = wa;
        Do[i] = wd;
    }
}

// Per batch: S = A_rows · D_rows^T, K=256, fp8-e4m3, MX-scaled MFMA
// (16x16x128, unit scales) -> 2x MFMA rate vs bf16 and only TWO k-steps.
// Whole K staged once into LDS (32KB+32KB), single barrier, no K-loop.
// 4-bit XOR swizzle (16 chunks of 16B per 256B row): staging stays
// lane-contiguous (global_load_lds HW requirement) while ds_read_b128 of
// 16 same-chunk rows spreads across banks (2-way = free).
// Epilogue: |.|-sum (invariant to any output permutation; A/B share the
// lane->k mapping so k-permutations cancel too) -> per-wave partial store.
__global__ __launch_bounds__(256) void gemm_abs_kernel(
    const unsigned char* __restrict__ Af8,
    const unsigned char* __restrict__ Df8,
    float* __restrict__ pg)
{
    __shared__ unsigned char lA[TM * CC];  // 32 KB
    __shared__ unsigned char lB[TM * CC];  // 32 KB

    const int b    = blockIdx.z;
    const int bm   = blockIdx.x * TM;
    const int bn   = blockIdx.y * TM;
    const int tid  = threadIdx.x;
    const int wave = tid >> 6;
    const int lane = tid & 63;
    const int wr   = wave >> 1, wc = wave & 1;

    const unsigned char* Agb = Af8 + (size_t)b * HWN * CC + (size_t)bm * CC;
    const unsigned char* Dgb = Df8 + (size_t)b * HWN * CC + (size_t)bn * CC;

    // Stage all of K: each wave covers rows [wave*32, wave*32+32) of both
    // tiles; one wave-op = 4 rows (64 lanes x 16B). Lane fetches the global
    // chunk that lands swizzled: store-chunk s=lane&15 holds logical chunk
    // s^(r&15).
    #pragma unroll
    for (int i = 0; i < 8; ++i) {
        const int r0 = wave * 32 + i * 4;
        const int r  = r0 + (lane >> 4);
        const int cs = (lane & 15) ^ (r & 15);
        const size_t gof = (size_t)r * CC + cs * 16;
        load_lds16(Agb + gof, (char*)lA + r0 * CC);
        load_lds16(Dgb + gof, (char*)lB + r0 * CC);
    }
    __syncthreads();   // vmcnt(0) drain: all staging visible

    floatx4 accf[4][4];
    #pragma unroll
    for (int mi = 0; mi < 4; ++mi)
        #pragma unroll
        for (int ni = 0; ni < 4; ++ni)
            accf[mi][ni] = (floatx4){0.f, 0.f, 0.f, 0.f};

    #pragma unroll
    for (int ks = 0; ks < 2; ++ks) {
        const int cb = ks * 8 + (lane >> 4) * 2;   // logical 16B chunk pair
        intx8 a8[4], b8[4];
        #pragma unroll
        for (int mi = 0; mi < 4; ++mi) {
            const int m = wr * 64 + mi * 16 + (lane & 15);
            const char* pa = (const char*)lA + m * CC;
            intx4 lo = *(const intx4*)(pa + ((cb    ) ^ (m & 15)) * 16);
            intx4 hi = *(const intx4*)(pa + ((cb + 1) ^ (m & 15)) * 16);
            a8[mi] = __builtin_shufflevector(lo, hi, 0, 1, 2, 3, 4, 5, 6, 7);
        }
        #pragma unroll
        for (int ni = 0; ni < 4; ++ni) {
            const int n = wc * 64 + ni * 16 + (lane & 15);
            const char* pb = (const char*)lB + n * CC;
            intx4 lo = *(const intx4*)(pb + ((cb    ) ^ (n & 15)) * 16);
            intx4 hi = *(const intx4*)(pb + ((cb + 1) ^ (n & 15)) * 16);
            b8[ni] = __builtin_shufflevector(lo, hi, 0, 1, 2, 3, 4, 5, 6, 7);
        }
        #pragma unroll
        for (int mi = 0; mi < 4; ++mi)
            #pragma unroll
            for (int ni = 0; ni < 4; ++ni)
                accf[mi][ni] = __builtin_amdgcn_mfma_scale_f32_16x16x128_f8f6f4(
                    a8[mi], b8[ni], accf[mi][ni],
                    0, 0,                      // cbsz=fp8, blgp=fp8
                    0, 0x7F7F7F7F,             // A scales: E8M0 1.0
                    0, 0x7F7F7F7F);            // B scales: E8M0 1.0
    }

    float s = 0.f;
    #pragma unroll
    for (int mi = 0; mi < 4; ++mi)
        #pragma unroll
        for (int ni = 0; ni < 4; ++ni)
            #pragma unroll
            for (int r = 0; r < 4; ++r)
                s += fabsf(accf[mi][ni][r]);
    #pragma unroll
    for (int off = 32; off > 0; off >>= 1) s += __shfl_down(s, off);
    if (lane == 0) {
        const int flat = blockIdx.x + 32 * (blockIdx.y + 32 * blockIdx.z);
        pg[flat * 4 + wave] = s;   // per-wave partial, zero contention
    }
}

// Single block: reduce 8192 match partials + 256 kp + 256 desc partials.
__global__ __launch_bounds__(256) void final_kernel(
    const float* __restrict__ pg, const float* __restrict__ pk,
    const float* __restrict__ pd, float* __restrict__ out)
{
    __shared__ float ws[4];
    const int t = threadIdx.x;
    float s = 0.f;
    #pragma unroll
    for (int i = 0; i < 32; ++i)
        s += pg[t + i * 256];
    s *= (1.0f / 33554432.0f);                 // match / (B*HW*HW)
    s += pk[t] * (1.0f / 8192.0f)              // kp / (B*HW)
       + pd[t] * (1.0f / 2097152.0f);          // desc / (B*C*HW)
    #pragma unroll
    for (int off = 32; off > 0; off >>= 1) s += __shfl_down(s, off);
    if ((t & 63) == 0) ws[t >> 6] = s;
    __syncthreads();
    if (t == 0) out[0] = ws[0] + ws[1] + ws[2] + ws[3];
}

extern "C" void kernel_launch(void* const* d_in, const int* in_sizes, int n_in,
                              void* d_out, int out_size, void* d_ws, size_t ws_size,
                              hipStream_t stream) {
    const float* sv = (const float*)d_in[0];
    const float* si = (const float*)d_in[1];
    const float* sf = (const float*)d_in[2];
    const float* dv = (const float*)d_in[3];
    const float* di = (const float*)d_in[4];
    const float* df = (const float*)d_in[5];

    unsigned char* Af8 = (unsigned char*)d_ws;                 // 2 MB
    unsigned char* Df8 = Af8 + (size_t)BB * HWN * CC;          // 2 MB
    float* pg = (float*)(Df8 + (size_t)BB * HWN * CC);         // 32 KB (8192)
    float* pk = pg + 8192;                                     // 1 KB (256)
    float* pd = pk + 256;                                      // 1 KB (256)

    prep_kernel<<<dim3(BB * (HWN / PT)), 1024, 0, stream>>>(
        sv, si, sf, dv, di, df, Af8, Df8, pk, pd);
    gemm_abs_kernel<<<dim3(HWN / TM, HWN / TM, BB), 256, 0, stream>>>(
        Af8, Df8, pg);
    final_kernel<<<1, 256, 0, stream>>>(pg, pk, pd, (float*)d_out);
}